// Round 5
// baseline (127.918 us; speedup 1.0000x reference)
//
#include <hip/hip_runtime.h>
#include <hip/hip_fp16.h>

// QLinear with per-k fp16 requantized accumulation (mptorch fma semantics).
// out = q16( q16_scan_fma( q8(x) @ q8(W)^T ) + q8(b) )
// __hfma2 (single RNE per fma) == reference fp32-mul/add/quant chain (fp32 add
// is exact for |acc|<64; data max ~6).
// R5: R1 matched a no-dedup LDS byte model exactly (compiler-pipelined plain
// intrinsics); R2-R4's inline-asm + slot-array pipeline defeated compiler
// scheduling (1.6x over model). Keep R4's 16 B/thread/k economics (64x64 tile,
// 4x4/thread, 2 waves/SIMD, dbuf) but splat x in registers via __low2half2/
// __high2half2 and accumulate with __hfma2 -- no asm, plain unrolled loop.

#define M_DIM 2048
#define N_DIM 1024
#define K_DIM 1024

#define BM 64
#define BN 64
#define BK 64
#define NCHUNK (K_DIM / BK)

// exact E4M3 (exp=4, man=3) quantization of an fp32 value, result fp32
__device__ __forceinline__ float quant_e4m3(float v) {
  unsigned au = __float_as_uint(v) & 0x7fffffffu;
  if (au == 0u) return v;                 // +-0
  int e = (int)(au >> 23) - 127;          // floor(log2|v|) for normals
  if (e < -6) e = -6;                     // fp32 subnorms hit the clamp too
  float s  = __uint_as_float((unsigned)(130 - e) << 23);  // 2^(3-e), exact
  float is = __uint_as_float((unsigned)(124 + e) << 23);  // 2^(e-3), exact
  float r = rintf(v * s) * is;            // RNE (half-to-even), all steps exact
  return fminf(240.f, fmaxf(-240.f, r));
}

// Fused prep: blocks [0,2048) transpose-quant x, [2048,3072) transpose-quant w.
__global__ __launch_bounds__(256) void prep_kernel(const float* __restrict__ x,
                                                   const float* __restrict__ w,
                                                   __half* __restrict__ xT,
                                                   __half* __restrict__ wT) {
  const int id = blockIdx.x;
  const float* in;
  __half* outp;
  int R, C, bx, by;
  if (id < 2048) { in = x; outp = xT; R = M_DIM; C = K_DIM; bx = id & 31; by = id >> 5; }
  else           { in = w; outp = wT; R = N_DIM; C = K_DIM; bx = (id - 2048) & 31; by = (id - 2048) >> 5; }

  __shared__ float tile[32][33];
  const int tx = threadIdx.x & 31;
  const int ty = threadIdx.x >> 5;
  const int c0 = bx * 32;
  const int r0 = by * 32;
#pragma unroll
  for (int i = 0; i < 4; i++) {
    int r = r0 + ty + i * 8;
    tile[ty + i * 8][tx] = quant_e4m3(in[(size_t)r * C + c0 + tx]);
  }
  __syncthreads();
#pragma unroll
  for (int i = 0; i < 4; i++) {
    int c = c0 + ty + i * 8;
    outp[(size_t)c * R + r0 + tx] = __float2half(tile[tx][ty + i * 8]);
  }
}

// xT [K][M] fp16, wT [K][N] fp16, b [N] fp32 (raw), out [M][N] fp32
__global__ __launch_bounds__(256) void gemm_qfma(const __half* __restrict__ xT,
                                                 const __half* __restrict__ wT,
                                                 const float* __restrict__ b,
                                                 float* __restrict__ outp) {
  __shared__ __half xs[2][BK][BM];   // 2 x 8 KB
  __shared__ __half wsh[2][BK][BN];  // 2 x 8 KB (32 KB total)

  const int tid = threadIdx.x;
  const int tn = tid & 15;   // 16 n-threads * 4 = BN
  const int tm = tid >> 4;   // 16 m-threads * 4 = BM
  const int tm4 = tm * 4, tn4 = tn * 4;
  const int bn0 = blockIdx.x * BN;
  const int bm0 = blockIdx.y * BM;

  __half2 acc[4][2];  // acc[i][j] = {C(m_i, n_{2j}), C(m_i, n_{2j+1})}
#pragma unroll
  for (int i = 0; i < 4; i++)
#pragma unroll
    for (int j = 0; j < 2; j++) acc[i][j] = __half2{__half(0.f), __half(0.f)};

  // staging: 8 threads x 8 halfs cover 64 cols; 32 rows per pass, 2 passes
  const int sr = tid >> 3, sc = (tid & 7) * 8;

  // global prefetch registers (chunk c+1 loaded during chunk c)
  uint4 gx[2], gw[2];
#pragma unroll
  for (int p = 0; p < 2; p++) {
    gx[p] = *reinterpret_cast<const uint4*>(xT + (size_t)(sr + p * 32) * M_DIM + bm0 + sc);
    gw[p] = *reinterpret_cast<const uint4*>(wT + (size_t)(sr + p * 32) * N_DIM + bn0 + sc);
  }

  for (int c = 0; c < NCHUNK; c++) {
    const int buf = c & 1;
#pragma unroll
    for (int p = 0; p < 2; p++) {
      *reinterpret_cast<uint4*>(&xs[buf][sr + p * 32][sc]) = gx[p];
      *reinterpret_cast<uint4*>(&wsh[buf][sr + p * 32][sc]) = gw[p];
    }

    if (c + 1 < NCHUNK) {  // prefetch next chunk during compute
      const int kn = (c + 1) * BK;
#pragma unroll
      for (int p = 0; p < 2; p++) {
        gx[p] = *reinterpret_cast<const uint4*>(xT + (size_t)(kn + sr + p * 32) * M_DIM + bm0 + sc);
        gw[p] = *reinterpret_cast<const uint4*>(wT + (size_t)(kn + sr + p * 32) * N_DIM + bn0 + sc);
      }
    }

    __syncthreads();

    const __half (*xsb)[BM] = xs[buf];
    const __half (*wsb)[BN] = wsh[buf];

#pragma unroll
    for (int kk = 0; kk < BK; kk++) {   // strictly ascending k (scan order)
      uint2 xu = *reinterpret_cast<const uint2*>(&xsb[kk][tm4]);
      uint2 wu = *reinterpret_cast<const uint2*>(&wsb[kk][tn4]);
      const __half2 xa = *reinterpret_cast<__half2*>(&xu.x);  // (m0,m1)
      const __half2 xb = *reinterpret_cast<__half2*>(&xu.y);  // (m2,m3)
      const __half2 wa = *reinterpret_cast<__half2*>(&wu.x);  // (n0,n1)
      const __half2 wb = *reinterpret_cast<__half2*>(&wu.y);  // (n2,n3)
      const __half2 x0 = __low2half2(xa),  x1 = __high2half2(xa);
      const __half2 x2 = __low2half2(xb),  x3 = __high2half2(xb);
      acc[0][0] = __hfma2(x0, wa, acc[0][0]); acc[0][1] = __hfma2(x0, wb, acc[0][1]);
      acc[1][0] = __hfma2(x1, wa, acc[1][0]); acc[1][1] = __hfma2(x1, wb, acc[1][1]);
      acc[2][0] = __hfma2(x2, wa, acc[2][0]); acc[2][1] = __hfma2(x2, wb, acc[2][1]);
      acc[3][0] = __hfma2(x3, wa, acc[3][0]); acc[3][1] = __hfma2(x3, wb, acc[3][1]);
    }
    __syncthreads();  // all reads of buf done before it is overwritten (c+2)
  }

  // epilogue: out = fp16RNE(acc + q8(b)), stored fp32 (fp32 add exact here)
  float4 bq = *reinterpret_cast<const float4*>(b + bn0 + tn4);
  bq.x = quant_e4m3(bq.x); bq.y = quant_e4m3(bq.y);
  bq.z = quant_e4m3(bq.z); bq.w = quant_e4m3(bq.w);
#pragma unroll
  for (int i = 0; i < 4; i++) {
    float4 o;
    o.x = __half2float(__float2half(__low2float(acc[i][0])  + bq.x));
    o.y = __half2float(__float2half(__high2float(acc[i][0]) + bq.y));
    o.z = __half2float(__float2half(__low2float(acc[i][1])  + bq.z));
    o.w = __half2float(__float2half(__high2float(acc[i][1]) + bq.w));
    *reinterpret_cast<float4*>(outp + (size_t)(bm0 + tm4 + i) * N_DIM + bn0 + tn4) = o;
  }
}

extern "C" void kernel_launch(void* const* d_in, const int* in_sizes, int n_in,
                              void* d_out, int out_size, void* d_ws, size_t ws_size,
                              hipStream_t stream) {
  const float* x = (const float*)d_in[0];   // [2048][1024]
  const float* w = (const float*)d_in[1];   // [1024][1024] (out_f, in_f)
  const float* b = (const float*)d_in[2];   // [1024]
  float* outp = (float*)d_out;              // [2048][1024] fp32

  char* ws = (char*)d_ws;
  __half* xT = (__half*)ws;                        // [K][M]  4 MiB
  __half* wT = (__half*)(ws + (size_t)(4 << 20));  // [K][N]  2 MiB

  hipLaunchKernelGGL(prep_kernel, dim3(3072), dim3(256), 0, stream,
                     x, w, xT, wT);
  hipLaunchKernelGGL(gemm_qfma, dim3(N_DIM / BN, M_DIM / BM), dim3(256), 0, stream,
                     xT, wT, b, outp);
}